// Round 1
// baseline (141.476 us; speedup 1.0000x reference)
//
#include <hip/hip_runtime.h>

#define TT 8192
#define DD 64
#define MODS 4
#define NCH 64
#define CH  128   // TT / NCH

// ---------------------------------------------------------------------------
// Kernel 1: the 5 MLPs (job 0 = Q from wq, jobs 1..4 = K_m from wk[m]).
// grid = (64 tiles of 128 rows, 5 jobs), block = 128 threads (2 waves).
// Thread computes an 8-row (stride 16) x 8-col register tile.
// x tile staged in LDS (pitch 68 -> conflict-free ds_read_b128);
// W read straight from global (16KB/layer, L1-resident, off the LDS pipe).
// ---------------------------------------------------------------------------
__global__ __launch_bounds__(128)
void mlp_kernel(const float* __restrict__ X,
                const float* __restrict__ wq_w, const float* __restrict__ wq_b,
                const float* __restrict__ wk_w, const float* __restrict__ wk_b,
                float* __restrict__ Q, float* __restrict__ Kout)
{
    __shared__ float xbuf[128 * 68];   // 34,816 B

    const int job  = blockIdx.y;
    const int tile = blockIdx.x;
    const float *xin, *W, *B;
    float* out;
    if (job == 0) { xin = X; W = wq_w; B = wq_b; out = Q; }
    else {
        const int m = job - 1;
        xin = X    + (size_t)m * TT * DD;
        W   = wk_w + (size_t)m * 3 * DD * DD;
        B   = wk_b + (size_t)m * 3 * DD;
        out = Kout + (size_t)m * TT * DD;
    }

    const int t    = threadIdx.x;
    const int row0 = tile * 128;

    // stage x tile: 128x64 floats, coalesced float4 loads
    {
        const float4* src4 = (const float4*)(xin + (size_t)row0 * DD);
        #pragma unroll
        for (int k2 = 0; k2 < 16; ++k2) {
            int f = t + 128 * k2;          // float4 index, 0..2047
            int r = f >> 4, c4 = (f & 15) << 2;
            *(float4*)(&xbuf[r * 68 + c4]) = src4[f];
        }
    }

    const int rg = t >> 3;          // 0..15
    const int c0 = (t & 7) << 3;    // 0,8,...,56
    float acc[8][8];

    #pragma unroll 1
    for (int l = 0; l < 3; ++l) {
        __syncthreads();            // staging / previous writeback visible
        const float* Wl = W + l * DD * DD;
        {
            float4 b0 = *(const float4*)(B + l * DD + c0);
            float4 b1 = *(const float4*)(B + l * DD + c0 + 4);
            #pragma unroll
            for (int i = 0; i < 8; ++i) {
                acc[i][0] = b0.x; acc[i][1] = b0.y; acc[i][2] = b0.z; acc[i][3] = b0.w;
                acc[i][4] = b1.x; acc[i][5] = b1.y; acc[i][6] = b1.z; acc[i][7] = b1.w;
            }
        }
        #pragma unroll 2
        for (int d = 0; d < DD; d += 4) {
            float w[4][8];
            #pragma unroll
            for (int dd = 0; dd < 4; ++dd) {
                *(float4*)&w[dd][0] = *(const float4*)(Wl + (d + dd) * DD + c0);
                *(float4*)&w[dd][4] = *(const float4*)(Wl + (d + dd) * DD + c0 + 4);
            }
            #pragma unroll
            for (int i = 0; i < 8; ++i) {
                const int r = rg + (i << 4);
                const float4 x4 = *(const float4*)(&xbuf[r * 68 + d]);
                #pragma unroll
                for (int j = 0; j < 8; ++j) acc[i][j] = fmaf(x4.x, w[0][j], acc[i][j]);
                #pragma unroll
                for (int j = 0; j < 8; ++j) acc[i][j] = fmaf(x4.y, w[1][j], acc[i][j]);
                #pragma unroll
                for (int j = 0; j < 8; ++j) acc[i][j] = fmaf(x4.z, w[2][j], acc[i][j]);
                #pragma unroll
                for (int j = 0; j < 8; ++j) acc[i][j] = fmaf(x4.w, w[3][j], acc[i][j]);
            }
        }
        __syncthreads();            // all xbuf reads done before overwrite
        if (l < 2) {
            #pragma unroll
            for (int i = 0; i < 8; ++i) {
                const int r = rg + (i << 4);
                float4 y0 = make_float4(fmaxf(acc[i][0], 0.f), fmaxf(acc[i][1], 0.f),
                                        fmaxf(acc[i][2], 0.f), fmaxf(acc[i][3], 0.f));
                float4 y1 = make_float4(fmaxf(acc[i][4], 0.f), fmaxf(acc[i][5], 0.f),
                                        fmaxf(acc[i][6], 0.f), fmaxf(acc[i][7], 0.f));
                *(float4*)(&xbuf[r * 68 + c0])     = y0;
                *(float4*)(&xbuf[r * 68 + c0 + 4]) = y1;
            }
        } else {
            #pragma unroll
            for (int i = 0; i < 8; ++i) {
                const int r = rg + (i << 4);
                *(float4*)(out + (size_t)(row0 + r) * DD + c0) =
                    make_float4(acc[i][0], acc[i][1], acc[i][2], acc[i][3]);
                *(float4*)(out + (size_t)(row0 + r) * DD + c0 + 4) =
                    make_float4(acc[i][4], acc[i][5], acc[i][6], acc[i][7]);
            }
        }
    }
}

// ---------------------------------------------------------------------------
// Kernel 2: per-chunk partial sums of K[t,d]*V[t,e]  (e in {0,1} only!).
// grid = (NCH, MODS), block = 128 (thread = e*64+d). Fully coalesced.
// ---------------------------------------------------------------------------
__global__ __launch_bounds__(128)
void scan_partial(const float* __restrict__ Kin, const float* __restrict__ X,
                  float* __restrict__ Ctot)
{
    const int m = blockIdx.y, ch = blockIdx.x;
    const int tid = threadIdx.x;
    const int d = tid & 63, e = tid >> 6;
    const float* Kb = Kin + ((size_t)m * TT + (size_t)ch * CH) * DD;
    const float* Vb = X   + ((size_t)m * TT + (size_t)ch * CH) * DD;
    float acc = 0.f;
    #pragma unroll 8
    for (int tt = 0; tt < CH; ++tt)
        acc = fmaf(Kb[tt * DD + d], Vb[tt * DD + e], acc);
    Ctot[((size_t)m * NCH + ch) * 128 + tid] = acc;
}

// ---------------------------------------------------------------------------
// Kernel 3: second pass — add exclusive chunk offsets, write inclusive
// prefix S[m][t][e][d] with coalesced 512B stores.
// ---------------------------------------------------------------------------
__global__ __launch_bounds__(128)
void scan_write(const float* __restrict__ Kin, const float* __restrict__ X,
                const float* __restrict__ Ctot, float* __restrict__ S)
{
    const int m = blockIdx.y, ch = blockIdx.x;
    const int tid = threadIdx.x;
    const int d = tid & 63, e = tid >> 6;
    float acc = 0.f;
    for (int c = 0; c < ch; ++c)
        acc += Ctot[((size_t)m * NCH + c) * 128 + tid];
    const float* Kb = Kin + ((size_t)m * TT + (size_t)ch * CH) * DD;
    const float* Vb = X   + ((size_t)m * TT + (size_t)ch * CH) * DD;
    float* Sb = S + ((size_t)m * TT + (size_t)ch * CH) * 2 * DD;
    #pragma unroll 4
    for (int tt = 0; tt < CH; ++tt) {
        acc = fmaf(Kb[tt * DD + d], Vb[tt * DD + e], acc);
        Sb[tt * 128 + tid] = acc;   // tid == e*64+d
    }
}

// ---------------------------------------------------------------------------
// Kernel 4: per-query gather. One wave per query. 4 interleaved binary
// searches (ILP over modalities), coalesced S reads, butterfly reduce.
// ---------------------------------------------------------------------------
__global__ __launch_bounds__(256)
void gather_kernel(const float* __restrict__ X, const float* __restrict__ Q,
                   const float* __restrict__ S, float* __restrict__ out)
{
    const int q    = (blockIdx.x << 2) + (threadIdx.x >> 6);
    const int lane = threadIdx.x & 63;
    const float t1 = X[(size_t)q * DD + 63];      // query time (modality 0)
    const float qv = Q[(size_t)q * DD + lane];

    const float* X1 = X + (size_t)TT * DD;
    const float* X2 = X + (size_t)2 * TT * DD;
    const float* X3 = X + (size_t)3 * TT * DD;

    int lo0 = 0, hi0 = TT, lo1 = 0, hi1 = TT;
    int lo2 = 0, hi2 = TT, lo3 = 0, hi3 = TT;
    #pragma unroll 1
    for (int s = 0; s < 13; ++s) {    // 2^13 == TT, exactly 13 steps
        int md0 = (lo0 + hi0) >> 1, md1 = (lo1 + hi1) >> 1;
        int md2 = (lo2 + hi2) >> 1, md3 = (lo3 + hi3) >> 1;
        float v0 = X [(size_t)md0 * DD + 63];
        float v1 = X1[(size_t)md1 * DD + 63];
        float v2 = X2[(size_t)md2 * DD + 63];
        float v3 = X3[(size_t)md3 * DD + 63];
        if (v0 <= t1) lo0 = md0 + 1; else hi0 = md0;
        if (v1 <= t1) lo1 = md1 + 1; else hi1 = md1;
        if (v2 <= t1) lo2 = md2 + 1; else hi2 = md2;
        if (v3 <= t1) lo3 = md3 + 1; else hi3 = md3;
    }

    float a0 = 0.f, a1 = 0.f;
    const int idx[4] = { lo0 - 1, lo1 - 1, lo2 - 1, lo3 - 1 };
    #pragma unroll
    for (int m = 0; m < MODS; ++m) {
        if (idx[m] >= 0) {
            const float* Srow = S + ((size_t)m * TT + idx[m]) * 2 * DD;
            a0 = fmaf(qv, Srow[lane],      a0);
            a1 = fmaf(qv, Srow[DD + lane], a1);
        }
    }
    #pragma unroll
    for (int off = 32; off > 0; off >>= 1) {
        a0 += __shfl_xor(a0, off, 64);
        a1 += __shfl_xor(a1, off, 64);
    }
    if (lane == 0) {
        out[(q << 1)]     = a0;
        out[(q << 1) + 1] = a1;
    }
}

extern "C" void kernel_launch(void* const* d_in, const int* in_sizes, int n_in,
                              void* d_out, int out_size, void* d_ws, size_t ws_size,
                              hipStream_t stream)
{
    const float* X    = (const float*)d_in[0];
    const float* wq_w = (const float*)d_in[1];
    const float* wq_b = (const float*)d_in[2];
    const float* wk_w = (const float*)d_in[3];
    const float* wk_b = (const float*)d_in[4];
    float* out = (float*)d_out;

    float* ws   = (float*)d_ws;
    float* Q    = ws;                                   // TT*DD            (2 MB)
    float* K    = Q    + (size_t)TT * DD;               // MODS*TT*DD       (8 MB)
    float* Ctot = K    + (size_t)MODS * TT * DD;        // MODS*NCH*128     (128 KB)
    float* S    = Ctot + (size_t)MODS * NCH * 128;      // MODS*TT*2*DD     (16 MB)

    mlp_kernel  <<<dim3(64, 5),       128, 0, stream>>>(X, wq_w, wq_b, wk_w, wk_b, Q, K);
    scan_partial<<<dim3(NCH, MODS),   128, 0, stream>>>(K, X, Ctot);
    scan_write  <<<dim3(NCH, MODS),   128, 0, stream>>>(K, X, Ctot, S);
    gather_kernel<<<TT / 4,           256, 0, stream>>>(X, Q, S, out);
}

// Round 2
// 132.162 us; speedup vs baseline: 1.0705x; 1.0705x over previous
//
#include <hip/hip_runtime.h>

#define TT 8192
#define DD 64
#define MODS 4
#define NCH 128
#define CH  64    // TT / NCH

// ---------------------------------------------------------------------------
// Kernel 1: the 5 MLPs (job 0 = Q from wq, jobs 1..4 = K_m from wk[m]).
// grid = (128 tiles of 64 rows, 5 jobs), block = 256 threads (4 waves)
// => 2560 waves total (2.5/SIMD) vs round-1's 640 (starved).
// Thread computes rows {rg, rg+32} x 8 cols. x tile in LDS (pitch 68,
// conflict-free); W read from global (L1-resident; TA merges the 8-lane
// duplicate addresses) to keep the LDS pipe at ~0.5 B/FMA.
// ---------------------------------------------------------------------------
__global__ __launch_bounds__(256)
void mlp_kernel(const float* __restrict__ X,
                const float* __restrict__ wq_w, const float* __restrict__ wq_b,
                const float* __restrict__ wk_w, const float* __restrict__ wk_b,
                float* __restrict__ Q, float* __restrict__ Kout)
{
    __shared__ float xbuf[64 * 68];   // 17,408 B -> LDS allows many blocks/CU

    const int job  = blockIdx.y;
    const int tile = blockIdx.x;
    const float *xin, *W, *B;
    float* out;
    if (job == 0) { xin = X; W = wq_w; B = wq_b; out = Q; }
    else {
        const int m = job - 1;
        xin = X    + (size_t)m * TT * DD;
        W   = wk_w + (size_t)m * 3 * DD * DD;
        B   = wk_b + (size_t)m * 3 * DD;
        out = Kout + (size_t)m * TT * DD;
    }

    const int t    = threadIdx.x;
    const int row0 = tile * 64;

    // stage x tile: 64x64 floats = 1024 float4, 4 per thread, coalesced
    {
        const float4* src4 = (const float4*)(xin + (size_t)row0 * DD);
        #pragma unroll
        for (int k2 = 0; k2 < 4; ++k2) {
            int f = t + 256 * k2;          // float4 index, 0..1023
            int r = f >> 4, c4 = (f & 15) << 2;
            *(float4*)(&xbuf[r * 68 + c4]) = src4[f];
        }
    }

    const int rg = t >> 3;          // 0..31
    const int c0 = (t & 7) << 3;    // 0,8,...,56
    float acc[2][8];

    #pragma unroll 1
    for (int l = 0; l < 3; ++l) {
        __syncthreads();            // staging / previous writeback visible
        const float* Wl = W + l * DD * DD;
        {
            float4 b0 = *(const float4*)(B + l * DD + c0);
            float4 b1 = *(const float4*)(B + l * DD + c0 + 4);
            #pragma unroll
            for (int i = 0; i < 2; ++i) {
                acc[i][0] = b0.x; acc[i][1] = b0.y; acc[i][2] = b0.z; acc[i][3] = b0.w;
                acc[i][4] = b1.x; acc[i][5] = b1.y; acc[i][6] = b1.z; acc[i][7] = b1.w;
            }
        }
        #pragma unroll 2
        for (int d = 0; d < DD; d += 4) {
            float w[4][8];
            #pragma unroll
            for (int dd = 0; dd < 4; ++dd) {
                *(float4*)&w[dd][0] = *(const float4*)(Wl + (d + dd) * DD + c0);
                *(float4*)&w[dd][4] = *(const float4*)(Wl + (d + dd) * DD + c0 + 4);
            }
            const float4 x0 = *(const float4*)(&xbuf[rg * 68 + d]);
            const float4 x1 = *(const float4*)(&xbuf[(rg + 32) * 68 + d]);
            #pragma unroll
            for (int j = 0; j < 8; ++j) acc[0][j] = fmaf(x0.x, w[0][j], acc[0][j]);
            #pragma unroll
            for (int j = 0; j < 8; ++j) acc[0][j] = fmaf(x0.y, w[1][j], acc[0][j]);
            #pragma unroll
            for (int j = 0; j < 8; ++j) acc[0][j] = fmaf(x0.z, w[2][j], acc[0][j]);
            #pragma unroll
            for (int j = 0; j < 8; ++j) acc[0][j] = fmaf(x0.w, w[3][j], acc[0][j]);
            #pragma unroll
            for (int j = 0; j < 8; ++j) acc[1][j] = fmaf(x1.x, w[0][j], acc[1][j]);
            #pragma unroll
            for (int j = 0; j < 8; ++j) acc[1][j] = fmaf(x1.y, w[1][j], acc[1][j]);
            #pragma unroll
            for (int j = 0; j < 8; ++j) acc[1][j] = fmaf(x1.z, w[2][j], acc[1][j]);
            #pragma unroll
            for (int j = 0; j < 8; ++j) acc[1][j] = fmaf(x1.w, w[3][j], acc[1][j]);
        }
        __syncthreads();            // all xbuf reads done before overwrite
        if (l < 2) {
            #pragma unroll
            for (int i = 0; i < 2; ++i) {
                const int r = rg + (i << 5);
                float4 y0 = make_float4(fmaxf(acc[i][0], 0.f), fmaxf(acc[i][1], 0.f),
                                        fmaxf(acc[i][2], 0.f), fmaxf(acc[i][3], 0.f));
                float4 y1 = make_float4(fmaxf(acc[i][4], 0.f), fmaxf(acc[i][5], 0.f),
                                        fmaxf(acc[i][6], 0.f), fmaxf(acc[i][7], 0.f));
                *(float4*)(&xbuf[r * 68 + c0])     = y0;
                *(float4*)(&xbuf[r * 68 + c0 + 4]) = y1;
            }
        } else {
            #pragma unroll
            for (int i = 0; i < 2; ++i) {
                const int r = rg + (i << 5);
                *(float4*)(out + (size_t)(row0 + r) * DD + c0) =
                    make_float4(acc[i][0], acc[i][1], acc[i][2], acc[i][3]);
                *(float4*)(out + (size_t)(row0 + r) * DD + c0 + 4) =
                    make_float4(acc[i][4], acc[i][5], acc[i][6], acc[i][7]);
            }
        }
    }
}

// ---------------------------------------------------------------------------
// Kernel 2: per-chunk partial sums of K[t,d]*V[t,e]  (e in {0,1} only!).
// grid = (NCH, MODS), block = 128 (thread = e*64+d). Fully coalesced.
// ---------------------------------------------------------------------------
__global__ __launch_bounds__(128)
void scan_partial(const float* __restrict__ Kin, const float* __restrict__ X,
                  float* __restrict__ Ctot)
{
    const int m = blockIdx.y, ch = blockIdx.x;
    const int tid = threadIdx.x;
    const int d = tid & 63, e = tid >> 6;
    const float* Kb = Kin + ((size_t)m * TT + (size_t)ch * CH) * DD;
    const float* Vb = X   + ((size_t)m * TT + (size_t)ch * CH) * DD;
    float acc = 0.f;
    #pragma unroll 8
    for (int tt = 0; tt < CH; ++tt)
        acc = fmaf(Kb[tt * DD + d], Vb[tt * DD + e], acc);
    Ctot[((size_t)m * NCH + ch) * 128 + tid] = acc;
}

// ---------------------------------------------------------------------------
// Kernel 3: second pass — add exclusive chunk offsets, write inclusive
// prefix S[m][t][e][d] with coalesced 512B stores.
// ---------------------------------------------------------------------------
__global__ __launch_bounds__(128)
void scan_write(const float* __restrict__ Kin, const float* __restrict__ X,
                const float* __restrict__ Ctot, float* __restrict__ S)
{
    const int m = blockIdx.y, ch = blockIdx.x;
    const int tid = threadIdx.x;
    const int d = tid & 63, e = tid >> 6;
    float acc = 0.f;
    #pragma unroll 4
    for (int c = 0; c < ch; ++c)
        acc += Ctot[((size_t)m * NCH + c) * 128 + tid];
    const float* Kb = Kin + ((size_t)m * TT + (size_t)ch * CH) * DD;
    const float* Vb = X   + ((size_t)m * TT + (size_t)ch * CH) * DD;
    float* Sb = S + ((size_t)m * TT + (size_t)ch * CH) * 2 * DD;
    #pragma unroll 4
    for (int tt = 0; tt < CH; ++tt) {
        acc = fmaf(Kb[tt * DD + d], Vb[tt * DD + e], acc);
        Sb[tt * 128 + tid] = acc;   // tid == e*64+d
    }
}

// ---------------------------------------------------------------------------
// Kernel 4: per-query gather. One wave per query. 4 interleaved binary
// searches (ILP over modalities), coalesced S reads, butterfly reduce.
// ---------------------------------------------------------------------------
__global__ __launch_bounds__(256)
void gather_kernel(const float* __restrict__ X, const float* __restrict__ Q,
                   const float* __restrict__ S, float* __restrict__ out)
{
    const int q    = (blockIdx.x << 2) + (threadIdx.x >> 6);
    const int lane = threadIdx.x & 63;
    const float t1 = X[(size_t)q * DD + 63];      // query time (modality 0)
    const float qv = Q[(size_t)q * DD + lane];

    const float* X1 = X + (size_t)TT * DD;
    const float* X2 = X + (size_t)2 * TT * DD;
    const float* X3 = X + (size_t)3 * TT * DD;

    int lo0 = 0, hi0 = TT, lo1 = 0, hi1 = TT;
    int lo2 = 0, hi2 = TT, lo3 = 0, hi3 = TT;
    #pragma unroll 1
    for (int s = 0; s < 13; ++s) {    // 2^13 == TT, exactly 13 steps
        int md0 = (lo0 + hi0) >> 1, md1 = (lo1 + hi1) >> 1;
        int md2 = (lo2 + hi2) >> 1, md3 = (lo3 + hi3) >> 1;
        float v0 = X [(size_t)md0 * DD + 63];
        float v1 = X1[(size_t)md1 * DD + 63];
        float v2 = X2[(size_t)md2 * DD + 63];
        float v3 = X3[(size_t)md3 * DD + 63];
        if (v0 <= t1) lo0 = md0 + 1; else hi0 = md0;
        if (v1 <= t1) lo1 = md1 + 1; else hi1 = md1;
        if (v2 <= t1) lo2 = md2 + 1; else hi2 = md2;
        if (v3 <= t1) lo3 = md3 + 1; else hi3 = md3;
    }

    float a0 = 0.f, a1 = 0.f;
    const int idx[4] = { lo0 - 1, lo1 - 1, lo2 - 1, lo3 - 1 };
    #pragma unroll
    for (int m = 0; m < MODS; ++m) {
        if (idx[m] >= 0) {
            const float* Srow = S + ((size_t)m * TT + idx[m]) * 2 * DD;
            a0 = fmaf(qv, Srow[lane],      a0);
            a1 = fmaf(qv, Srow[DD + lane], a1);
        }
    }
    #pragma unroll
    for (int off = 32; off > 0; off >>= 1) {
        a0 += __shfl_xor(a0, off, 64);
        a1 += __shfl_xor(a1, off, 64);
    }
    if (lane == 0) {
        out[(q << 1)]     = a0;
        out[(q << 1) + 1] = a1;
    }
}

extern "C" void kernel_launch(void* const* d_in, const int* in_sizes, int n_in,
                              void* d_out, int out_size, void* d_ws, size_t ws_size,
                              hipStream_t stream)
{
    const float* X    = (const float*)d_in[0];
    const float* wq_w = (const float*)d_in[1];
    const float* wq_b = (const float*)d_in[2];
    const float* wk_w = (const float*)d_in[3];
    const float* wk_b = (const float*)d_in[4];
    float* out = (float*)d_out;

    float* ws   = (float*)d_ws;
    float* Q    = ws;                                   // TT*DD            (2 MB)
    float* K    = Q    + (size_t)TT * DD;               // MODS*TT*DD       (8 MB)
    float* Ctot = K    + (size_t)MODS * TT * DD;        // MODS*NCH*128     (256 KB)
    float* S    = Ctot + (size_t)MODS * NCH * 128;      // MODS*TT*2*DD     (16 MB)

    mlp_kernel  <<<dim3(128, 5),      256, 0, stream>>>(X, wq_w, wq_b, wk_w, wk_b, Q, K);
    scan_partial<<<dim3(NCH, MODS),   128, 0, stream>>>(K, X, Ctot);
    scan_write  <<<dim3(NCH, MODS),   128, 0, stream>>>(K, X, Ctot, S);
    gather_kernel<<<TT / 4,           256, 0, stream>>>(X, Q, S, out);
}

// Round 3
// 109.920 us; speedup vs baseline: 1.2871x; 1.2023x over previous
//
#include <hip/hip_runtime.h>

#define TT 8192
#define DD 64
#define MODS 4
#define NJOBS 5
#define NCH 128
#define CH  64    // TT / NCH

typedef __attribute__((ext_vector_type(8))) short bf16x8;
typedef __attribute__((ext_vector_type(4))) float f32x4;

// round-to-nearest-even fp32 -> bf16 bits
__device__ __forceinline__ unsigned f2bf1(float x) {
    unsigned u = __float_as_uint(x);
    return (u + 0x7FFFu + ((u >> 16) & 1u)) >> 16;
}
__device__ __forceinline__ unsigned packbf(float a, float b) {
    return f2bf1(a) | (f2bf1(b) << 16);
}

// ---------------------------------------------------------------------------
// Kernel 0: W -> W^T bf16. Output WT[job][lin][c][d], pitch 64 bf16.
// 15 blocks (job*3+lin), 256 threads. LDS tile transpose, coalesced in+out.
// ---------------------------------------------------------------------------
__global__ __launch_bounds__(256)
void wt_prep(const float* __restrict__ wq_w, const float* __restrict__ wk_w,
             unsigned short* __restrict__ WT)
{
    __shared__ float tile[64 * 65];
    const int b = blockIdx.x;                 // 0..14
    const float* Wsrc = (b < 3) ? (wq_w + (size_t)b * 4096)
                                : (wk_w + (size_t)(b - 3) * 4096);
    const int t = threadIdx.x;
    #pragma unroll
    for (int k = 0; k < 16; ++k) {
        int i = t + 256 * k;                  // 0..4095, W[d][c]
        tile[(i >> 6) * 65 + (i & 63)] = Wsrc[i];
    }
    __syncthreads();
    unsigned* dst = (unsigned*)(WT + (size_t)b * 4096);
    #pragma unroll
    for (int k = 0; k < 8; ++k) {
        int u = t + 256 * k;                  // b32 unit: c = u>>5, dw = u&31
        int c = u >> 5, dw = u & 31;
        float a  = tile[(2 * dw)     * 65 + c];
        float bb = tile[(2 * dw + 1) * 65 + c];
        dst[c * 32 + dw] = packbf(a, bb);     // WT[c][2dw],[2dw+1]
    }
}

// ---------------------------------------------------------------------------
// Kernel 1: the 5 MLPs via bf16 MFMA, computing y^T = W^T x^T per layer.
// grid = (TT/64, 5 jobs), block 256 = 4 waves; each wave owns 16 rows.
//   A-frag = WT[c][d] from GLOBAL (bf16, L1-hot, zero lane duplication)
//   B-frag = x rows from LDS (pitch 72 bf16, bank-balanced b128)
//   C lane layout: col(lane&15)=row r, rowC(quad*4+reg)=output col c
//   -> layer transition = relu + pack + ONE ds_write_b64 per frag.
// Waves touch only their own 16 LDS rows: NO barriers at all.
// ---------------------------------------------------------------------------
__global__ __launch_bounds__(256)
void mlp_kernel(const float* __restrict__ X,
                const unsigned short* __restrict__ WT,
                const float* __restrict__ wq_b, const float* __restrict__ wk_b,
                float* __restrict__ Q, float* __restrict__ Kout)
{
    __shared__ unsigned short xbuf[4][16][72];   // 9,216 B

    const int job = blockIdx.y;
    const float* xin;
    const float* Bias;
    float* out;
    if (job == 0) { xin = X; Bias = wq_b; out = Q; }
    else {
        const int m = job - 1;
        xin  = X    + (size_t)m * TT * DD;
        Bias = wk_b + (size_t)m * 3 * DD;
        out  = Kout + (size_t)m * TT * DD;
    }
    const unsigned short* WTj = WT + (size_t)job * 3 * DD * DD;

    const int wv   = threadIdx.x >> 6;
    const int lane = threadIdx.x & 63;
    const int quad = lane >> 4;
    const int l15  = lane & 15;
    const int row0 = blockIdx.x * 64 + wv * 16;   // this wave's 16 rows
    unsigned short* xb = &xbuf[wv][0][0];         // [16][72]

    // ---- stage this wave's 16x64 fp32 rows as bf16 into LDS ----
    {
        const float4* src = (const float4*)(xin + (size_t)row0 * DD);
        #pragma unroll
        for (int k = 0; k < 4; ++k) {
            int f = lane + 64 * k;                // float4 idx 0..255
            int r = f >> 4, c4 = (f & 15) << 2;   // row, col
            float4 v = src[f];
            uint2 p = make_uint2(packbf(v.x, v.y), packbf(v.z, v.w));
            *(uint2*)&xb[r * 72 + c4] = p;        // 8B aligned
        }
    }

    #pragma unroll
    for (int l = 0; l < 3; ++l) {
        const unsigned short* WTl = WTj + (size_t)l * DD * DD;  // [c][d]
        const float* Bl = Bias + l * DD;

        f32x4 acc[4];
        #pragma unroll
        for (int mt = 0; mt < 4; ++mt) {          // acc init = bias (C operand)
            float4 b4 = *(const float4*)(Bl + 16 * mt + quad * 4);
            acc[mt][0] = b4.x; acc[mt][1] = b4.y; acc[mt][2] = b4.z; acc[mt][3] = b4.w;
        }

        bf16x8 xf[2];                             // B-frags: x[r=l15][k=quad*8+j+32kt]
        #pragma unroll
        for (int kt = 0; kt < 2; ++kt)
            xf[kt] = *(const bf16x8*)&xb[l15 * 72 + quad * 8 + kt * 32];

        #pragma unroll
        for (int mt = 0; mt < 4; ++mt) {
            #pragma unroll
            for (int kt = 0; kt < 2; ++kt) {
                // A-frag: WT[c=l15+16mt][d=quad*8+j+32kt], contiguous b128
                bf16x8 wf = *(const bf16x8*)&WTl[(size_t)(16 * mt + l15) * DD + quad * 8 + kt * 32];
                acc[mt] = __builtin_amdgcn_mfma_f32_16x16x32_bf16(wf, xf[kt], acc[mt], 0, 0, 0);
            }
        }

        if (l < 2) {                              // relu + pack + writeback
            #pragma unroll
            for (int mt = 0; mt < 4; ++mt) {
                float r0 = fmaxf(acc[mt][0], 0.f), r1 = fmaxf(acc[mt][1], 0.f);
                float r2 = fmaxf(acc[mt][2], 0.f), r3 = fmaxf(acc[mt][3], 0.f);
                uint2 p = make_uint2(packbf(r0, r1), packbf(r2, r3));
                // cols c = 16mt + quad*4 .. +3 of row r=l15
                *(uint2*)&xb[l15 * 72 + 16 * mt + quad * 4] = p;
            }
        } else {                                  // final: store fp32
            #pragma unroll
            for (int mt = 0; mt < 4; ++mt) {
                float4 v = make_float4(acc[mt][0], acc[mt][1], acc[mt][2], acc[mt][3]);
                *(float4*)(out + (size_t)(row0 + l15) * DD + 16 * mt + quad * 4) = v;
            }
        }
    }
}

// ---------------------------------------------------------------------------
// Kernel 2: per-chunk partial sums of K[t,d]*V[t,e]  (e in {0,1} only).
// ---------------------------------------------------------------------------
__global__ __launch_bounds__(128)
void scan_partial(const float* __restrict__ Kin, const float* __restrict__ X,
                  float* __restrict__ Ctot)
{
    const int m = blockIdx.y, ch = blockIdx.x;
    const int tid = threadIdx.x;
    const int d = tid & 63, e = tid >> 6;
    const float* Kb = Kin + ((size_t)m * TT + (size_t)ch * CH) * DD;
    const float* Vb = X   + ((size_t)m * TT + (size_t)ch * CH) * DD;
    float acc = 0.f;
    #pragma unroll 8
    for (int tt = 0; tt < CH; ++tt)
        acc = fmaf(Kb[tt * DD + d], Vb[tt * DD + e], acc);
    Ctot[((size_t)m * NCH + ch) * 128 + tid] = acc;
}

// ---------------------------------------------------------------------------
// Kernel 3: add exclusive chunk offsets, write inclusive prefix
// S[m][t][e][d] with coalesced 512B stores.
// ---------------------------------------------------------------------------
__global__ __launch_bounds__(128)
void scan_write(const float* __restrict__ Kin, const float* __restrict__ X,
                const float* __restrict__ Ctot, float* __restrict__ S)
{
    const int m = blockIdx.y, ch = blockIdx.x;
    const int tid = threadIdx.x;
    const int d = tid & 63, e = tid >> 6;
    float acc = 0.f;
    #pragma unroll 4
    for (int c = 0; c < ch; ++c)
        acc += Ctot[((size_t)m * NCH + c) * 128 + tid];
    const float* Kb = Kin + ((size_t)m * TT + (size_t)ch * CH) * DD;
    const float* Vb = X   + ((size_t)m * TT + (size_t)ch * CH) * DD;
    float* Sb = S + ((size_t)m * TT + (size_t)ch * CH) * 2 * DD;
    #pragma unroll 4
    for (int tt = 0; tt < CH; ++tt) {
        acc = fmaf(Kb[tt * DD + d], Vb[tt * DD + e], acc);
        Sb[tt * 128 + tid] = acc;   // tid == e*64+d
    }
}

// ---------------------------------------------------------------------------
// Kernel 4: per-query gather. One wave per query; 4 interleaved binary
// searches; coalesced S reads; butterfly reduce.
// ---------------------------------------------------------------------------
__global__ __launch_bounds__(256)
void gather_kernel(const float* __restrict__ X, const float* __restrict__ Q,
                   const float* __restrict__ S, float* __restrict__ out)
{
    const int q    = (blockIdx.x << 2) + (threadIdx.x >> 6);
    const int lane = threadIdx.x & 63;
    const float t1 = X[(size_t)q * DD + 63];
    const float qv = Q[(size_t)q * DD + lane];

    const float* X1 = X + (size_t)TT * DD;
    const float* X2 = X + (size_t)2 * TT * DD;
    const float* X3 = X + (size_t)3 * TT * DD;

    int lo0 = 0, hi0 = TT, lo1 = 0, hi1 = TT;
    int lo2 = 0, hi2 = TT, lo3 = 0, hi3 = TT;
    #pragma unroll 1
    for (int s = 0; s < 13; ++s) {
        int md0 = (lo0 + hi0) >> 1, md1 = (lo1 + hi1) >> 1;
        int md2 = (lo2 + hi2) >> 1, md3 = (lo3 + hi3) >> 1;
        float v0 = X [(size_t)md0 * DD + 63];
        float v1 = X1[(size_t)md1 * DD + 63];
        float v2 = X2[(size_t)md2 * DD + 63];
        float v3 = X3[(size_t)md3 * DD + 63];
        if (v0 <= t1) lo0 = md0 + 1; else hi0 = md0;
        if (v1 <= t1) lo1 = md1 + 1; else hi1 = md1;
        if (v2 <= t1) lo2 = md2 + 1; else hi2 = md2;
        if (v3 <= t1) lo3 = md3 + 1; else hi3 = md3;
    }

    float a0 = 0.f, a1 = 0.f;
    const int idx[4] = { lo0 - 1, lo1 - 1, lo2 - 1, lo3 - 1 };
    #pragma unroll
    for (int m = 0; m < MODS; ++m) {
        if (idx[m] >= 0) {
            const float* Srow = S + ((size_t)m * TT + idx[m]) * 2 * DD;
            a0 = fmaf(qv, Srow[lane],      a0);
            a1 = fmaf(qv, Srow[DD + lane], a1);
        }
    }
    #pragma unroll
    for (int off = 32; off > 0; off >>= 1) {
        a0 += __shfl_xor(a0, off, 64);
        a1 += __shfl_xor(a1, off, 64);
    }
    if (lane == 0) {
        out[(q << 1)]     = a0;
        out[(q << 1) + 1] = a1;
    }
}

extern "C" void kernel_launch(void* const* d_in, const int* in_sizes, int n_in,
                              void* d_out, int out_size, void* d_ws, size_t ws_size,
                              hipStream_t stream)
{
    const float* X    = (const float*)d_in[0];
    const float* wq_w = (const float*)d_in[1];
    const float* wq_b = (const float*)d_in[2];
    const float* wk_w = (const float*)d_in[3];
    const float* wk_b = (const float*)d_in[4];
    float* out = (float*)d_out;

    // workspace layout
    unsigned short* WT = (unsigned short*)d_ws;          // 15*4096 bf16 = 122,880 B
    float* fws  = (float*)((char*)d_ws + 15 * 4096 * sizeof(unsigned short));
    float* Q    = fws;                                   // TT*DD            (2 MB)
    float* K    = Q    + (size_t)TT * DD;                // MODS*TT*DD       (8 MB)
    float* Ctot = K    + (size_t)MODS * TT * DD;         // MODS*NCH*128     (256 KB)
    float* S    = Ctot + (size_t)MODS * NCH * 128;       // MODS*TT*2*DD     (16 MB)

    wt_prep     <<<15,              256, 0, stream>>>(wq_w, wk_w, WT);
    mlp_kernel  <<<dim3(TT/64, 5),  256, 0, stream>>>(X, WT, wq_b, wk_b, Q, K);
    scan_partial<<<dim3(NCH, MODS), 128, 0, stream>>>(K, X, Ctot);
    scan_write  <<<dim3(NCH, MODS), 128, 0, stream>>>(K, X, Ctot, S);
    gather_kernel<<<TT / 4,         256, 0, stream>>>(X, Q, S, out);
}